// Round 1
// baseline (3542.739 us; speedup 1.0000x reference)
//
#include <hip/hip_runtime.h>
#include <math.h>

// ---------------------------------------------------------------------------
// DynamicPerceiverEncoder forward, f32 correctness-first implementation.
// B=4, D=768, NH=8, dh=96, latents=256, patches=196, visible=49,
// L=6 blocks, E=8 experts (top-2), FF hidden=1536.
// ---------------------------------------------------------------------------

namespace {

constexpr int Dm  = 768;
constexpr int NH_ = 8;
constexpr int DH_ = 96;
constexpr int ML  = 256;   // latent tokens
constexpr int BB  = 4;     // batch
constexpr int NP  = 196;   // patches
constexpr int NV  = 49;    // visible
constexpr int NE  = 8;     // experts
constexpr int FH_ = 1536;  // ff hidden
constexpr int NL  = 6;     // layers
constexpr int NT  = 1024;  // BB*ML tokens
constexpr int NPAIR = 2048;

// workspace offsets (in floats)
constexpr long OFF_LAT   = 0;                      // 786432
constexpr long OFF_QKV   = 786432;                 // 2359296 (aliases MoE O-buf)
constexpr long OFF_S     = OFF_QKV + 2359296;      // 3145728 (aliases H-buf)
constexpr long OFF_AO    = OFF_S + 3145728;        // 786432
constexpr long OFF_TMP   = OFF_AO + 786432;        // 786432
constexpr long OFF_PATCH = OFF_TMP + 786432;       // 602112
constexpr long OFF_VIS   = OFF_PATCH + 602112;     // 150528
constexpr long OFF_QQ    = OFF_VIS + 150528;       // 196608
constexpr long OFF_KKVV  = OFF_QQ + 196608;        // 301056
constexpr long OFF_TOPW  = OFF_KKVV + 301056;      // 2048
constexpr long OFF_INT   = OFF_TOPW + 2048;        // int region

// ---------------- block reductions (256 threads, 4 waves) ----------------
__device__ __forceinline__ float blk_sum(float v, float* sh){
#pragma unroll
  for (int off = 32; off; off >>= 1) v += __shfl_xor(v, off);
  int wid = threadIdx.x >> 6;
  if ((threadIdx.x & 63) == 0) sh[wid] = v;
  __syncthreads();
  v = sh[0] + sh[1] + sh[2] + sh[3];
  __syncthreads();
  return v;
}
__device__ __forceinline__ float blk_max(float v, float* sh){
#pragma unroll
  for (int off = 32; off; off >>= 1) v = fmaxf(v, __shfl_xor(v, off));
  int wid = threadIdx.x >> 6;
  if ((threadIdx.x & 63) == 0) sh[wid] = v;
  __syncthreads();
  v = fmaxf(fmaxf(sh[0], sh[1]), fmaxf(sh[2], sh[3]));
  __syncthreads();
  return v;
}

// ---------------- patch embed: conv16x16 stride16 + pos + type ----------------
__global__ __launch_bounds__(256) void patch_embed_k(
    const float* __restrict__ images, const int* __restrict__ type_ids,
    const float* __restrict__ conv_w, const float* __restrict__ conv_b,
    const float* __restrict__ type_emb, float* __restrict__ patches)
{
  int bp = blockIdx.x;
  int b = bp / NP, p = bp % NP;
  int ph = p / 14, pw = p % 14;
  __shared__ __align__(16) float xs[768];
  int tid = threadIdx.x;
  int kh = tid >> 4, kw = tid & 15;
#pragma unroll
  for (int c = 0; c < 3; c++)
    xs[c * 256 + tid] = images[((b * 3 + c) * 224 + ph * 16 + kh) * 224 + pw * 16 + kw];
  __syncthreads();
  int ty = type_ids[b];
#pragma unroll
  for (int jj = 0; jj < 3; jj++){
    int d = tid + jj * 256;
    const float4* wv = (const float4*)(conv_w + (long)d * 768);
    const float4* xv = (const float4*)xs;
    float s = 0.f;
    for (int k = 0; k < 192; k++){
      float4 w4 = wv[k], x4 = xv[k];
      s += w4.x * x4.x + w4.y * x4.y + w4.z * x4.z + w4.w * x4.w;
    }
    s += conv_b[d];
    int q = d % 192, sect = d / 192;
    float omega = powf(10000.0f, -(float)q / 192.0f);
    float arg = (sect < 2 ? (float)pw : (float)ph) * omega;
    float pos = ((sect & 1) == 0) ? sinf(arg) : cosf(arg);
    s += pos + type_emb[(long)ty * Dm + d];
    patches[(long)bp * Dm + d] = s;
  }
}

// ---------------- stable argsort of 196 noise values per batch ----------------
__global__ __launch_bounds__(256) void argsort_k(
    const float* __restrict__ noise, int* __restrict__ ids,
    float* __restrict__ out_keep, float* __restrict__ out_mask)
{
  int b = blockIdx.x, tid = threadIdx.x;
  __shared__ float v[NP];
  __shared__ int ord[NP];
  if (tid < NP) v[tid] = noise[b * NP + tid];
  __syncthreads();
  if (tid < NP){
    float x = v[tid];
    int rank = 0;
    for (int j = 0; j < NP; j++){
      float y = v[j];
      rank += (y < x) || (y == x && j < tid);
    }
    ord[rank] = tid;
  }
  __syncthreads();
  if (tid < NP){
    int id = ord[tid];
    ids[b * NP + tid] = id;
    if (tid < NV) out_keep[b * NV + tid] = (float)id;
    else          out_mask[b * (NP - NV) + (tid - NV)] = (float)id;
  }
}

__global__ __launch_bounds__(256) void gather_k(
    const float* __restrict__ patches, const int* __restrict__ ids,
    float* __restrict__ visible)
{
  int bv = blockIdx.x;
  int b = bv / NV, v = bv % NV;
  int src = ids[b * NP + v];
  const float* in = patches + ((long)b * NP + src) * Dm;
  float* out = visible + (long)bv * Dm;
  for (int j = threadIdx.x; j < Dm; j += 256) out[j] = in[j];
}

// ---------------- generic tiled GEMM ----------------
// C[z][M,N] = alpha * A[z] (M,K) * op(B[z]) + bias; BT: B is (N,K) row-major
// (dot of rows); !BT: B is (K,N) row-major. z decomposed as (zb, zh) = (z/NH, z%NH).
template<bool BT>
__global__ __launch_bounds__(256) void gemm_k(
    const float* __restrict__ A, int lda, long aSB, int aSH,
    const float* __restrict__ B, int ldb, long bSB, int bSH,
    float* __restrict__ C, int ldc, long cSB, int cSH,
    int M, int N, int K, int Krows, int NHd,
    const float* __restrict__ bias, float alpha, int act)
{
  int z = blockIdx.z, zb = z / NHd, zh = z - zb * NHd;
  const float* Ab = A + (long)zb * aSB + (long)zh * aSH;
  const float* Bb = B + (long)zb * bSB + (long)zh * bSH;
  float*       Cb = C + (long)zb * cSB + (long)zh * cSH;
  int m0 = blockIdx.y << 6, n0 = blockIdx.x << 6;
  __shared__ __align__(16) float As[16][68];
  __shared__ __align__(16) float Bs[16][68];
  int tid = threadIdx.x;
  int lr = tid >> 2, lc = (tid & 3) << 2;      // 64x16 loader
  int br = tid >> 4, bc = (tid & 15) << 2;     // 16x64 loader (!BT)
  int ty = tid >> 4, tx = tid & 15;
  float acc[4][4] = {};
  for (int k0 = 0; k0 < K; k0 += 16){
    {
      float4 av = make_float4(0.f, 0.f, 0.f, 0.f);
      int arow = m0 + lr;
      if (arow < M) av = *(const float4*)(Ab + (long)arow * lda + k0 + lc);
      As[lc + 0][lr] = av.x; As[lc + 1][lr] = av.y;
      As[lc + 2][lr] = av.z; As[lc + 3][lr] = av.w;
    }
    if (BT){
      float4 bv = make_float4(0.f, 0.f, 0.f, 0.f);
      int brow = n0 + lr;
      if (brow < N) bv = *(const float4*)(Bb + (long)brow * ldb + k0 + lc);
      Bs[lc + 0][lr] = bv.x; Bs[lc + 1][lr] = bv.y;
      Bs[lc + 2][lr] = bv.z; Bs[lc + 3][lr] = bv.w;
    } else {
      float4 bv = make_float4(0.f, 0.f, 0.f, 0.f);
      int krow = k0 + br;
      if (krow < Krows) bv = *(const float4*)(Bb + (long)krow * ldb + n0 + bc);
      Bs[br][bc + 0] = bv.x; Bs[br][bc + 1] = bv.y;
      Bs[br][bc + 2] = bv.z; Bs[br][bc + 3] = bv.w;
    }
    __syncthreads();
#pragma unroll
    for (int kk = 0; kk < 16; kk++){
      float4 a4 = *(const float4*)&As[kk][ty << 2];
      float4 b4 = *(const float4*)&Bs[kk][tx << 2];
      float ar[4] = {a4.x, a4.y, a4.z, a4.w};
      float brr[4] = {b4.x, b4.y, b4.z, b4.w};
#pragma unroll
      for (int i = 0; i < 4; i++)
#pragma unroll
        for (int j = 0; j < 4; j++)
          acc[i][j] = fmaf(ar[i], brr[j], acc[i][j]);
    }
    __syncthreads();
  }
#pragma unroll
  for (int i = 0; i < 4; i++){
    int row = m0 + (ty << 2) + i;
    if (row >= M) continue;
#pragma unroll
    for (int j = 0; j < 4; j++){
      int col = n0 + (tx << 2) + j;
      if (col >= N) continue;
      float v = acc[i][j] * alpha;
      if (bias) v += bias[col];
      if (act == 1) v = 0.5f * v * (1.0f + erff(v * 0.70710678118654752f));
      Cb[(long)row * ldc + col] = v;
    }
  }
}

// ---------------- row softmax (len <= ld <= 256) ----------------
__global__ __launch_bounds__(256) void softmax_k(float* __restrict__ S, int len, int ld)
{
  long row = blockIdx.x;
  float* p = S + row * (long)ld;
  int j = threadIdx.x;
  __shared__ float sh[4];
  float x = (j < len) ? p[j] : -1e30f;
  float m = blk_max(x, sh);
  float e = (j < len) ? __expf(x - m) : 0.0f;
  float s = blk_sum(e, sh);
  if (j < ld) p[j] = e / s;   // pads [len,ld) get exact zeros
}

// ---------------- add residual + layernorm ----------------
__global__ __launch_bounds__(256) void add_ln_k(
    const float* __restrict__ X, const float* __restrict__ R, int rMod,
    const float* __restrict__ w, const float* __restrict__ b, float* __restrict__ out)
{
  int row = blockIdx.x;
  int rrow = rMod ? (row % rMod) : row;
  __shared__ float sh[4];
  float x[3];
#pragma unroll
  for (int i = 0; i < 3; i++){
    int d = threadIdx.x + (i << 8);
    x[i] = X[(long)row * Dm + d] + R[(long)rrow * Dm + d];
  }
  float s = blk_sum(x[0] + x[1] + x[2], sh);
  float mean = s * (1.0f / 768.0f);
  float vs = 0.f;
#pragma unroll
  for (int i = 0; i < 3; i++){ float t = x[i] - mean; vs += t * t; }
  vs = blk_sum(vs, sh);
  float rstd = rsqrtf(vs * (1.0f / 768.0f) + 1e-5f);
#pragma unroll
  for (int i = 0; i < 3; i++){
    int d = threadIdx.x + (i << 8);
    out[(long)row * Dm + d] = (x[i] - mean) * rstd * w[d] + b[d];
  }
}

// ---------------- MoE router: softmax(x@rw^T+rb), top-2, renorm ----------------
__global__ __launch_bounds__(256) void router_k(
    const float* __restrict__ lat, const float* __restrict__ rw, const float* __restrict__ rb,
    int* __restrict__ top_idx, float* __restrict__ top_w)
{
  int t = blockIdx.x, tid = threadIdx.x;
  int e = tid >> 5, lane = tid & 31;
  const float* x = lat + (long)t * Dm;
  const float* w = rw + (long)e * Dm;
  float s = 0.f;
  for (int j = 0; j < 24; j++){ int d = lane + 32 * j; s += x[d] * w[d]; }
#pragma unroll
  for (int off = 16; off; off >>= 1) s += __shfl_xor(s, off);
  __shared__ float lg[NE];
  if (lane == 0) lg[e] = s + rb[e];
  __syncthreads();
  if (tid == 0){
    float m = -1e30f;
    for (int i = 0; i < NE; i++) m = fmaxf(m, lg[i]);
    float p[NE]; float se = 0.f;
    for (int i = 0; i < NE; i++){ p[i] = __expf(lg[i] - m); se += p[i]; }
    float inv = 1.0f / se;
    int i0 = 0, i1 = -1; float v0 = -1.f, v1 = -1.f;
    for (int i = 0; i < NE; i++){
      float pi = p[i] * inv;
      if (pi > v0){ v1 = v0; i1 = i0; v0 = pi; i0 = i; }
      else if (pi > v1){ v1 = pi; i1 = i; }
    }
    float w0 = 1.0f / (1.0f + __expf(v1 - v0));  // softmax([v0,v1])
    top_idx[2 * t] = i0; top_idx[2 * t + 1] = i1;
    top_w[2 * t] = w0;   top_w[2 * t + 1] = 1.0f - w0;
  }
}

// ---------------- group token-expert pairs by expert ----------------
__global__ __launch_bounds__(256) void scatter_k(
    const int* __restrict__ top_idx, int* __restrict__ counts, int* __restrict__ offsets,
    int* __restrict__ ptok, int* __restrict__ posmap)
{
  __shared__ int cnt[NE], cur[NE];
  int tid = threadIdx.x;
  if (tid < NE) cnt[tid] = 0;
  __syncthreads();
  for (int t = tid; t < NT; t += 256){
    atomicAdd(&cnt[top_idx[2 * t]], 1);
    atomicAdd(&cnt[top_idx[2 * t + 1]], 1);
  }
  __syncthreads();
  if (tid == 0){
    int o = 0;
    for (int e = 0; e < NE; e++){ offsets[e] = o; cur[e] = o; counts[e] = cnt[e]; o += cnt[e]; }
  }
  __syncthreads();
  for (int t = tid; t < NT; t += 256){
#pragma unroll
    for (int sidx = 0; sidx < 2; sidx++){
      int e = top_idx[2 * t + sidx];
      int pos = atomicAdd(&cur[e], 1);
      ptok[pos] = t;
      posmap[2 * t + sidx] = pos;
    }
  }
}

// ---------------- expert-grouped GEMM (gathered rows, early-exit blocks) ----------------
template<bool GATHER, bool GELU>
__global__ __launch_bounds__(256) void moe_gemm_k(
    const float* __restrict__ A, int lda,
    const float* __restrict__ W, long wE, int ldw,
    const float* __restrict__ bias, int bE,
    float* __restrict__ C, int ldc, int N, int K,
    const int* __restrict__ counts, const int* __restrict__ offsets,
    const int* __restrict__ ptok)
{
  int e = blockIdx.y >> 5, mb = blockIdx.y & 31;
  int cnt = counts[e];
  if (mb * 64 >= cnt) return;
  int off = offsets[e];
  const float* Wb = W + (long)e * wE;
  const float* bb = bias + (long)e * bE;
  int n0 = blockIdx.x << 6;
  __shared__ __align__(16) float As[16][68];
  __shared__ __align__(16) float Bs[16][68];
  int tid = threadIdx.x;
  int lr = tid >> 2, lc = (tid & 3) << 2;
  int ty = tid >> 4, tx = tid & 15;
  float acc[4][4] = {};
  for (int k0 = 0; k0 < K; k0 += 16){
    {
      float4 av = make_float4(0.f, 0.f, 0.f, 0.f);
      int gl = (mb << 6) + lr;
      if (gl < cnt){
        long arow = GATHER ? (long)ptok[off + gl] : (long)(off + gl);
        av = *(const float4*)(A + arow * lda + k0 + lc);
      }
      As[lc + 0][lr] = av.x; As[lc + 1][lr] = av.y;
      As[lc + 2][lr] = av.z; As[lc + 3][lr] = av.w;
    }
    {
      float4 bv = make_float4(0.f, 0.f, 0.f, 0.f);
      int wrow = n0 + lr;
      if (wrow < N) bv = *(const float4*)(Wb + (long)wrow * ldw + k0 + lc);
      Bs[lc + 0][lr] = bv.x; Bs[lc + 1][lr] = bv.y;
      Bs[lc + 2][lr] = bv.z; Bs[lc + 3][lr] = bv.w;
    }
    __syncthreads();
#pragma unroll
    for (int kk = 0; kk < 16; kk++){
      float4 a4 = *(const float4*)&As[kk][ty << 2];
      float4 b4 = *(const float4*)&Bs[kk][tx << 2];
      float ar[4] = {a4.x, a4.y, a4.z, a4.w};
      float brr[4] = {b4.x, b4.y, b4.z, b4.w};
#pragma unroll
      for (int i = 0; i < 4; i++)
#pragma unroll
        for (int j = 0; j < 4; j++)
          acc[i][j] = fmaf(ar[i], brr[j], acc[i][j]);
    }
    __syncthreads();
  }
#pragma unroll
  for (int i = 0; i < 4; i++){
    int gl = (mb << 6) + (ty << 2) + i;
    if (gl >= cnt) continue;
    long grow = off + gl;
#pragma unroll
    for (int j = 0; j < 4; j++){
      int col = n0 + (tx << 2) + j;
      if (col >= N) continue;
      float v = acc[i][j] + bb[col];
      if (GELU) v = 0.5f * v * (1.0f + erff(v * 0.70710678118654752f));
      C[grow * ldc + col] = v;
    }
  }
}

// ---------------- MoE combine (top-2 weighted) + residual + LN ----------------
__global__ __launch_bounds__(256) void moe_combine_ln_k(
    const float* __restrict__ OBuf, const int* __restrict__ posmap, const float* __restrict__ topw,
    const float* __restrict__ latin, const float* __restrict__ w, const float* __restrict__ b,
    float* __restrict__ lat)
{
  int t = blockIdx.x;
  int p0 = posmap[2 * t], p1 = posmap[2 * t + 1];
  float w0 = topw[2 * t], w1 = topw[2 * t + 1];
  __shared__ float sh[4];
  float x[3];
#pragma unroll
  for (int i = 0; i < 3; i++){
    int d = threadIdx.x + (i << 8);
    x[i] = w0 * OBuf[(long)p0 * Dm + d] + w1 * OBuf[(long)p1 * Dm + d] + latin[(long)t * Dm + d];
  }
  float s = blk_sum(x[0] + x[1] + x[2], sh);
  float mean = s * (1.0f / 768.0f);
  float vs = 0.f;
#pragma unroll
  for (int i = 0; i < 3; i++){ float tt = x[i] - mean; vs += tt * tt; }
  vs = blk_sum(vs, sh);
  float rstd = rsqrtf(vs * (1.0f / 768.0f) + 1e-5f);
#pragma unroll
  for (int i = 0; i < 3; i++){
    int d = threadIdx.x + (i << 8);
    lat[(long)t * Dm + d] = (x[i] - mean) * rstd * w[d] + b[d];
  }
}

__global__ __launch_bounds__(256) void copy_k(const float* __restrict__ in, float* __restrict__ out)
{
  long i = (long)blockIdx.x * 256 + threadIdx.x;
  out[i] = in[i];
}

} // namespace

extern "C" void kernel_launch(void* const* d_in, const int* in_sizes, int n_in,
                              void* d_out, int out_size, void* d_ws, size_t ws_size,
                              hipStream_t stream)
{
  (void)in_sizes; (void)n_in; (void)out_size; (void)ws_size;
  const float* images    = (const float*)d_in[0];
  const int*   type_ids  = (const int*)d_in[1];
  const float* noise     = (const float*)d_in[2];
  const float* conv_w    = (const float*)d_in[3];
  const float* conv_b    = (const float*)d_in[4];
  const float* latents   = (const float*)d_in[5];
  const float* type_emb  = (const float*)d_in[6];
  const float* ca_in_w   = (const float*)d_in[7];
  const float* ca_in_b   = (const float*)d_in[8];
  const float* ca_out_w  = (const float*)d_in[9];
  const float* ca_out_b  = (const float*)d_in[10];
  const float* ca_ln_w   = (const float*)d_in[11];
  const float* ca_ln_b   = (const float*)d_in[12];
  const float* blk_in_w  = (const float*)d_in[13];
  const float* blk_in_b  = (const float*)d_in[14];
  const float* blk_out_w = (const float*)d_in[15];
  const float* blk_out_b = (const float*)d_in[16];
  const float* blk_ln1_w = (const float*)d_in[17];
  const float* blk_ln1_b = (const float*)d_in[18];
  const float* blk_ln2_w = (const float*)d_in[19];
  const float* blk_ln2_b = (const float*)d_in[20];
  const float* router_w  = (const float*)d_in[21];
  const float* router_b  = (const float*)d_in[22];
  const float* e_w1      = (const float*)d_in[23];
  const float* e_b1      = (const float*)d_in[24];
  const float* e_w2      = (const float*)d_in[25];
  const float* e_b2      = (const float*)d_in[26];

  float* ws      = (float*)d_ws;
  float* lat     = ws + OFF_LAT;
  float* qkv     = ws + OFF_QKV;
  float* obufM   = ws + OFF_QKV;   // alias (disjoint in time)
  float* S       = ws + OFF_S;
  float* Hbuf    = ws + OFF_S;     // alias (disjoint in time)
  float* ao      = ws + OFF_AO;
  float* tmp     = ws + OFF_TMP;
  float* patches = ws + OFF_PATCH;
  float* visible = ws + OFF_VIS;
  float* qq      = ws + OFF_QQ;
  float* kkvv    = ws + OFF_KKVV;
  float* topw    = ws + OFF_TOPW;
  int*   ibase   = (int*)(ws + OFF_INT);
  int*   ids     = ibase;
  int*   top_idx = ibase + 784;
  int*   posmap  = top_idx + 2048;
  int*   ptok    = posmap + 2048;
  int*   counts  = ptok + 2048;
  int*   offsets = counts + 8;

  float* out      = (float*)d_out;
  float* out_lat  = out;
  float* out_keep = out + (long)NT * Dm;                 // 786432
  float* out_mask = out_keep + BB * NV;                  // +196

  dim3 blk(256);
  const float inv_sqrt_dh = 1.0f / sqrtf((float)DH_);

  // ---- prologue ----
  patch_embed_k<<<BB * NP, blk, 0, stream>>>(images, type_ids, conv_w, conv_b, type_emb, patches);
  argsort_k<<<BB, blk, 0, stream>>>(noise, ids, out_keep, out_mask);
  gather_k<<<BB * NV, blk, 0, stream>>>(patches, ids, visible);

  // ---- cross attention ----
  // qq = latents @ wq^T + bq (batch-invariant)
  gemm_k<true><<<dim3(12, 4, 1), blk, 0, stream>>>(
      latents, Dm, 0, 0, ca_in_w, Dm, 0, 0, qq, Dm, 0, 0,
      ML, Dm, Dm, Dm, 1, ca_in_b, 1.0f, 0);
  // kkvv = visible @ [wk;wv]^T + b
  gemm_k<true><<<dim3(24, 4, 1), blk, 0, stream>>>(
      visible, Dm, 0, 0, ca_in_w + 768 * 768, Dm, 0, 0, kkvv, 1536, 0, 0,
      BB * NV, 1536, Dm, Dm, 1, ca_in_b + 768, 1.0f, 0);
  // scores (B*NH batches): S[z] = qq @ K^T / sqrt(dh), ld=64 padded
  gemm_k<true><<<dim3(1, 4, BB * NH_), blk, 0, stream>>>(
      qq, Dm, 0, DH_,
      kkvv, 1536, (long)NV * 1536, DH_,
      S, 64, (long)NH_ * ML * 64, ML * 64,
      ML, NV, DH_, DH_, NH_, nullptr, inv_sqrt_dh, 0);
  softmax_k<<<BB * NH_ * ML, blk, 0, stream>>>(S, NV, 64);
  // PV
  gemm_k<false><<<dim3(2, 4, BB * NH_), blk, 0, stream>>>(
      S, 64, (long)NH_ * ML * 64, ML * 64,
      kkvv + 768, 1536, (long)NV * 1536, DH_,
      ao, Dm, (long)ML * Dm, DH_,
      ML, DH_, 64, NV, NH_, nullptr, 1.0f, 0);
  // out proj
  gemm_k<true><<<dim3(12, 16, 1), blk, 0, stream>>>(
      ao, Dm, 0, 0, ca_out_w, Dm, 0, 0, tmp, Dm, 0, 0,
      NT, Dm, Dm, Dm, 1, ca_out_b, 1.0f, 0);
  add_ln_k<<<NT, blk, 0, stream>>>(tmp, latents, ML, ca_ln_w, ca_ln_b, lat);

  // ---- transformer blocks ----
  for (int l = 0; l < NL; l++){
    // qkv projection
    gemm_k<true><<<dim3(36, 16, 1), blk, 0, stream>>>(
        lat, Dm, 0, 0, blk_in_w + (long)l * 2304 * 768, Dm, 0, 0,
        qkv, 2304, 0, 0, NT, 2304, Dm, Dm, 1, blk_in_b + (long)l * 2304, 1.0f, 0);
    // scores
    gemm_k<true><<<dim3(4, 4, BB * NH_), blk, 0, stream>>>(
        qkv, 2304, (long)ML * 2304, DH_,
        qkv + 768, 2304, (long)ML * 2304, DH_,
        S, ML, (long)NH_ * ML * ML, ML * ML,
        ML, ML, DH_, DH_, NH_, nullptr, inv_sqrt_dh, 0);
    softmax_k<<<BB * NH_ * ML, blk, 0, stream>>>(S, ML, ML);
    // PV
    gemm_k<false><<<dim3(2, 4, BB * NH_), blk, 0, stream>>>(
        S, ML, (long)NH_ * ML * ML, ML * ML,
        qkv + 1536, 2304, (long)ML * 2304, DH_,
        ao, Dm, (long)ML * Dm, DH_,
        ML, DH_, ML, ML, NH_, nullptr, 1.0f, 0);
    // out proj
    gemm_k<true><<<dim3(12, 16, 1), blk, 0, stream>>>(
        ao, Dm, 0, 0, blk_out_w + (long)l * 768 * 768, Dm, 0, 0, tmp, Dm, 0, 0,
        NT, Dm, Dm, Dm, 1, blk_out_b + (long)l * 768, 1.0f, 0);
    add_ln_k<<<NT, blk, 0, stream>>>(tmp, lat, 0,
        blk_ln1_w + (long)l * 768, blk_ln1_b + (long)l * 768, lat);

    // MoE (top-2 only)
    router_k<<<NT, blk, 0, stream>>>(lat, router_w + (long)l * NE * Dm, router_b + (long)l * NE,
                                     top_idx, topw);
    scatter_k<<<1, blk, 0, stream>>>(top_idx, counts, offsets, ptok, posmap);
    moe_gemm_k<true, true><<<dim3(24, 256, 1), blk, 0, stream>>>(
        lat, Dm,
        e_w1 + (long)l * NE * FH_ * Dm, (long)FH_ * Dm, Dm,
        e_b1 + (long)l * NE * FH_, FH_,
        Hbuf, FH_, FH_, Dm, counts, offsets, ptok);
    moe_gemm_k<false, false><<<dim3(12, 256, 1), blk, 0, stream>>>(
        Hbuf, FH_,
        e_w2 + (long)l * NE * Dm * FH_, (long)Dm * FH_, FH_,
        e_b2 + (long)l * NE * Dm, Dm,
        obufM, Dm, Dm, FH_, counts, offsets, ptok);
    moe_combine_ln_k<<<NT, blk, 0, stream>>>(obufM, posmap, topw, lat,
        blk_ln2_w + (long)l * 768, blk_ln2_b + (long)l * 768, lat);
  }

  copy_k<<<NT * Dm / 256, blk, 0, stream>>>(lat, out_lat);
}

// Round 2
// 2141.894 us; speedup vs baseline: 1.6540x; 1.6540x over previous
//
#include <hip/hip_runtime.h>
#include <math.h>

// ---------------------------------------------------------------------------
// DynamicPerceiverEncoder forward — bf16 MFMA GEMMs, f32 elsewhere.
// B=4, D=768, NH=8, dh=96, latents=256, visible=49, L=6, E=8 (top-2), FF=1536.
// ---------------------------------------------------------------------------

namespace {

constexpr int Dm  = 768;
constexpr int NH_ = 8;
constexpr int DH_ = 96;
constexpr int ML  = 256;
constexpr int BB  = 4;
constexpr int NP  = 196;
constexpr int NV  = 49;
constexpr int NE  = 8;
constexpr int FH_ = 1536;
constexpr int NL  = 6;
constexpr int NT  = 1024;

// workspace offsets (floats)
constexpr long OFF_LAT   = 0;                      // 786432
constexpr long OFF_QKV   = 786432;                 // 2359296 (alias: MoE O-buf 1572864)
constexpr long OFF_S     = OFF_QKV + 2359296;      // 3145728 (alias: H-buf 3145728)
constexpr long OFF_AO    = OFF_S + 3145728;        // 786432
constexpr long OFF_TMP   = OFF_AO + 786432;        // 786432
constexpr long OFF_COL   = OFF_TMP + 786432;       // 150528 (visible im2col)
constexpr long OFF_VIS   = OFF_COL + 150528;       // 150528
constexpr long OFF_QQ    = OFF_VIS + 150528;       // 196608
constexpr long OFF_KKVV  = OFF_QQ + 196608;        // 301056
constexpr long OFF_TOPW  = OFF_KKVV + 301056;      // 2048
constexpr long OFF_INT   = OFF_TOPW + 2048;

typedef __attribute__((ext_vector_type(8))) short bf16x8;
typedef __attribute__((ext_vector_type(4))) float f32x4;

__device__ __forceinline__ short f2bf(float f){
  union { float f; unsigned u; } v; v.f = f;
  unsigned r = v.u + 0x7fffu + ((v.u >> 16) & 1u);
  return (short)(r >> 16);
}
__device__ __forceinline__ void pack8(const float4& a, const float4& b, bf16x8& w){
  w[0]=f2bf(a.x); w[1]=f2bf(a.y); w[2]=f2bf(a.z); w[3]=f2bf(a.w);
  w[4]=f2bf(b.x); w[5]=f2bf(b.y); w[6]=f2bf(b.z); w[7]=f2bf(b.w);
}

// ---------------- block reductions (256 threads, 4 waves) ----------------
__device__ __forceinline__ float blk_sum(float v, float* sh){
#pragma unroll
  for (int off = 32; off; off >>= 1) v += __shfl_xor(v, off);
  int wid = threadIdx.x >> 6;
  if ((threadIdx.x & 63) == 0) sh[wid] = v;
  __syncthreads();
  v = sh[0] + sh[1] + sh[2] + sh[3];
  __syncthreads();
  return v;
}
__device__ __forceinline__ float blk_max(float v, float* sh){
#pragma unroll
  for (int off = 32; off; off >>= 1) v = fmaxf(v, __shfl_xor(v, off));
  int wid = threadIdx.x >> 6;
  if ((threadIdx.x & 63) == 0) sh[wid] = v;
  __syncthreads();
  v = fmaxf(fmaxf(sh[0], sh[1]), fmaxf(sh[2], sh[3]));
  __syncthreads();
  return v;
}

// ---------------- argsort of 196 noise values per batch (stable) ----------------
__global__ __launch_bounds__(256) void argsort_k(
    const float* __restrict__ noise, int* __restrict__ ids,
    float* __restrict__ out_keep, float* __restrict__ out_mask)
{
  int b = blockIdx.x, tid = threadIdx.x;
  __shared__ float v[NP];
  __shared__ int ord[NP];
  if (tid < NP) v[tid] = noise[b * NP + tid];
  __syncthreads();
  if (tid < NP){
    float x = v[tid];
    int rank = 0;
    for (int j = 0; j < NP; j++){
      float y = v[j];
      rank += (y < x) || (y == x && j < tid);
    }
    ord[rank] = tid;
  }
  __syncthreads();
  if (tid < NP){
    int id = ord[tid];
    ids[b * NP + tid] = id;
    if (tid < NV) out_keep[b * NV + tid] = (float)id;
    else          out_mask[b * (NP - NV) + (tid - NV)] = (float)id;
  }
}

// ---------------- im2col of VISIBLE patches only ----------------
__global__ __launch_bounds__(256) void im2col_k(
    const float* __restrict__ images, const int* __restrict__ ids,
    float* __restrict__ col)
{
  int bv = blockIdx.x;
  int b = bv / NV, v = bv % NV;
  int pid = ids[b * NP + v];
  int ph = pid / 14, pw = pid % 14;
  int t = threadIdx.x;
  int kh = t >> 4, kw = t & 15;
#pragma unroll
  for (int c = 0; c < 3; c++)
    col[(long)bv * Dm + c * 256 + t] =
      images[((b * 3 + c) * 224 + ph * 16 + kh) * 224 + pw * 16 + kw];
}

// ---------------- pos-emb + type-emb add (visible only) ----------------
__global__ __launch_bounds__(256) void pos_type_k(
    float* __restrict__ visible, const int* __restrict__ ids,
    const int* __restrict__ type_ids, const float* __restrict__ type_emb)
{
  int bv = blockIdx.x;
  int b = bv / NV, v = bv % NV;
  int pid = ids[b * NP + v];
  int ph = pid / 14, pw = pid % 14;
  int ty = type_ids[b];
  int t = threadIdx.x;
#pragma unroll
  for (int jj = 0; jj < 3; jj++){
    int d = t + (jj << 8);
    int q = d % 192, sect = d / 192;
    float omega = powf(10000.0f, -(float)q / 192.0f);
    float arg = (sect < 2 ? (float)pw : (float)ph) * omega;
    float pos = ((sect & 1) == 0) ? sinf(arg) : cosf(arg);
    visible[(long)bv * Dm + d] += pos + type_emb[(long)ty * Dm + d];
  }
}

// ---------------- bf16 MFMA GEMM: 128x128 tile, BK=32, 4 waves ----------------
// C[z][M,N] = alpha * A (M,K) * op(B) + bias, optional GELU.
// BT: B is (N,K) row-major. !BT: B is (Krows,N) row-major (k>=Krows -> 0).
// MOE: blockIdx.y = e*mbPerE + mb; rows are expert-grouped positions;
//      GATHER: A row = ptok[pos]; else A row = pos. B/bias per-expert via bSB/biasE.
template<bool BT, bool MOE, bool GATHER>
__global__ __launch_bounds__(256) void mgemm_k(
    const float* __restrict__ A, int lda, long aSB, int aSH,
    const float* __restrict__ B, int ldb, long bSB, int bSH,
    float* __restrict__ C, int ldc, long cSB, int cSH,
    int M, int N, int K, int Krows, int NHd,
    const float* __restrict__ bias, int biasE, float alpha, int act,
    const int* __restrict__ counts, const int* __restrict__ offsets,
    const int* __restrict__ ptok, int mbPerE)
{
  __shared__ short lsa[4096];   // [4][128][8] bf16
  __shared__ short lsb[4096];
  int t = threadIdx.x;

  int m0, cnt = 0, off = 0;
  const float *Ab, *Bb, *bb;
  float* Cb;
  if (MOE){
    int e = blockIdx.y / mbPerE, mb = blockIdx.y - e * mbPerE;
    cnt = counts[e];
    m0 = mb << 7;
    if (m0 >= cnt) return;
    off = offsets[e];
    Ab = A;
    Bb = B + (long)e * bSB;
    bb = bias + (long)e * biasE;
    Cb = C;
  } else {
    int z = blockIdx.z, zb = z / NHd, zh = z - zb * NHd;
    Ab = A + (long)zb * aSB + (long)zh * aSH;
    Bb = B + (long)zb * bSB + (long)zh * bSH;
    Cb = C + (long)zb * cSB + (long)zh * cSH;
    bb = bias;
    m0 = blockIdx.y << 7;
  }
  int n0 = blockIdx.x << 7;

  int srow = t >> 1;              // 0..127
  int skh  = (t & 1) << 4;        // 0 / 16
  int c0   = skh >> 3;            // 0 / 2

  const float* aptr = nullptr;
  {
    int gl = m0 + srow;
    bool ok = MOE ? (gl < cnt) : (gl < M);
    if (ok){
      long ar = MOE ? (GATHER ? (long)ptok[off + gl] : (long)(off + gl)) : (long)gl;
      aptr = Ab + ar * (long)lda + skh;
    }
  }
  const float* bptr = nullptr;
  if (BT){
    int gc = n0 + srow;
    if (gc < N) bptr = Bb + (long)gc * ldb + skh;
  }

  f32x4 acc[4][4];
#pragma unroll
  for (int m = 0; m < 4; m++)
#pragma unroll
    for (int n = 0; n < 4; n++)
      acc[m][n] = (f32x4){0.f, 0.f, 0.f, 0.f};

  int lane = t & 63, wid = t >> 6;
  int wr = wid >> 1, wc = wid & 1;
  int fr = lane & 15, lk = lane >> 4;

  for (int k0 = 0; k0 < K; k0 += 32){
    // stage A
    {
      float4 x0 = make_float4(0,0,0,0), x1 = x0, x2 = x0, x3 = x0;
      if (aptr){
        const float4* p = (const float4*)(aptr + k0);
        x0 = p[0]; x1 = p[1]; x2 = p[2]; x3 = p[3];
      }
      bf16x8 w0, w1;
      pack8(x0, x1, w0); pack8(x2, x3, w1);
      *(bf16x8*)&lsa[((c0    ) * 128 + srow) * 8] = w0;
      *(bf16x8*)&lsa[((c0 + 1) * 128 + srow) * 8] = w1;
    }
    // stage B
    if (BT){
      float4 x0 = make_float4(0,0,0,0), x1 = x0, x2 = x0, x3 = x0;
      if (bptr){
        const float4* p = (const float4*)(bptr + k0);
        x0 = p[0]; x1 = p[1]; x2 = p[2]; x3 = p[3];
      }
      bf16x8 w0, w1;
      pack8(x0, x1, w0); pack8(x2, x3, w1);
      *(bf16x8*)&lsb[((c0    ) * 128 + srow) * 8] = w0;
      *(bf16x8*)&lsb[((c0 + 1) * 128 + srow) * 8] = w1;
    } else {
      int kr = t >> 5;             // 0..7
      int nc = (t & 31) << 2;      // 0..124
#pragma unroll
      for (int i = 0; i < 4; i++){
        int k = k0 + (i << 3) + kr;
        float4 v = make_float4(0,0,0,0);
        if (k < Krows){
          int nb = n0 + nc;
          const float* bp = Bb + (long)k * ldb;
          if (nb + 3 < N) v = *(const float4*)(bp + nb);
          else {
            if (nb     < N) v.x = bp[nb];
            if (nb + 1 < N) v.y = bp[nb + 1];
            if (nb + 2 < N) v.z = bp[nb + 2];
            if (nb + 3 < N) v.w = bp[nb + 3];
          }
        }
        int base = ((i << 7) + nc) * 8 + kr;
        lsb[base     ] = f2bf(v.x);
        lsb[base +  8] = f2bf(v.y);
        lsb[base + 16] = f2bf(v.z);
        lsb[base + 24] = f2bf(v.w);
      }
    }
    __syncthreads();

    bf16x8 av[4], bv[4];
#pragma unroll
    for (int m = 0; m < 4; m++)
      av[m] = *(const bf16x8*)&lsa[(lk * 128 + wr * 64 + m * 16 + fr) * 8];
#pragma unroll
    for (int n = 0; n < 4; n++)
      bv[n] = *(const bf16x8*)&lsb[(lk * 128 + wc * 64 + n * 16 + fr) * 8];
#pragma unroll
    for (int m = 0; m < 4; m++)
#pragma unroll
      for (int n = 0; n < 4; n++)
        acc[m][n] = __builtin_amdgcn_mfma_f32_16x16x32_bf16(av[m], bv[n], acc[m][n], 0, 0, 0);
    __syncthreads();
  }

  // epilogue
#pragma unroll
  for (int m = 0; m < 4; m++){
#pragma unroll
    for (int i = 0; i < 4; i++){
      int rl = m0 + wr * 64 + m * 16 + lk * 4 + i;
      bool rok = MOE ? (rl < cnt) : (rl < M);
      if (!rok) continue;
      long grow = MOE ? (long)(off + rl) : (long)rl;
#pragma unroll
      for (int n = 0; n < 4; n++){
        int col = n0 + wc * 64 + n * 16 + fr;
        if (col >= N) continue;
        float v = acc[m][n][i] * alpha;
        if (bb) v += bb[col];
        if (act) v = 0.5f * v * (1.0f + erff(v * 0.70710678118654752f));
        Cb[grow * (long)ldc + col] = v;
      }
    }
  }
}

// ---------------- row softmax (len <= ld <= 256) ----------------
__global__ __launch_bounds__(256) void softmax_k(float* __restrict__ S, int len, int ld)
{
  long row = blockIdx.x;
  float* p = S + row * (long)ld;
  int j = threadIdx.x;
  __shared__ float sh[4];
  float x = (j < len) ? p[j] : -1e30f;
  float m = blk_max(x, sh);
  float e = (j < len) ? __expf(x - m) : 0.0f;
  float s = blk_sum(e, sh);
  if (j < ld) p[j] = e / s;
}

// ---------------- add residual + layernorm ----------------
__global__ __launch_bounds__(256) void add_ln_k(
    const float* __restrict__ X, const float* __restrict__ R, int rMod,
    const float* __restrict__ w, const float* __restrict__ b, float* __restrict__ out)
{
  int row = blockIdx.x;
  int rrow = rMod ? (row % rMod) : row;
  __shared__ float sh[4];
  float x[3];
#pragma unroll
  for (int i = 0; i < 3; i++){
    int d = threadIdx.x + (i << 8);
    x[i] = X[(long)row * Dm + d] + R[(long)rrow * Dm + d];
  }
  float s = blk_sum(x[0] + x[1] + x[2], sh);
  float mean = s * (1.0f / 768.0f);
  float vs = 0.f;
#pragma unroll
  for (int i = 0; i < 3; i++){ float t = x[i] - mean; vs += t * t; }
  vs = blk_sum(vs, sh);
  float rstd = rsqrtf(vs * (1.0f / 768.0f) + 1e-5f);
#pragma unroll
  for (int i = 0; i < 3; i++){
    int d = threadIdx.x + (i << 8);
    out[(long)row * Dm + d] = (x[i] - mean) * rstd * w[d] + b[d];
  }
}

// ---------------- MoE router ----------------
__global__ __launch_bounds__(256) void router_k(
    const float* __restrict__ lat, const float* __restrict__ rw, const float* __restrict__ rb,
    int* __restrict__ top_idx, float* __restrict__ top_w)
{
  int t = blockIdx.x, tid = threadIdx.x;
  int e = tid >> 5, lane = tid & 31;
  const float* x = lat + (long)t * Dm;
  const float* w = rw + (long)e * Dm;
  float s = 0.f;
  for (int j = 0; j < 24; j++){ int d = lane + 32 * j; s += x[d] * w[d]; }
#pragma unroll
  for (int off = 16; off; off >>= 1) s += __shfl_xor(s, off);
  __shared__ float lg[NE];
  if (lane == 0) lg[e] = s + rb[e];
  __syncthreads();
  if (tid == 0){
    float m = -1e30f;
    for (int i = 0; i < NE; i++) m = fmaxf(m, lg[i]);
    float p[NE]; float se = 0.f;
    for (int i = 0; i < NE; i++){ p[i] = __expf(lg[i] - m); se += p[i]; }
    float inv = 1.0f / se;
    int i0 = 0, i1 = -1; float v0 = -1.f, v1 = -1.f;
    for (int i = 0; i < NE; i++){
      float pi = p[i] * inv;
      if (pi > v0){ v1 = v0; i1 = i0; v0 = pi; i0 = i; }
      else if (pi > v1){ v1 = pi; i1 = i; }
    }
    float w0 = 1.0f / (1.0f + __expf(v1 - v0));
    top_idx[2 * t] = i0; top_idx[2 * t + 1] = i1;
    top_w[2 * t] = w0;   top_w[2 * t + 1] = 1.0f - w0;
  }
}

// ---------------- group token-expert pairs by expert ----------------
__global__ __launch_bounds__(256) void scatter_k(
    const int* __restrict__ top_idx, int* __restrict__ counts, int* __restrict__ offsets,
    int* __restrict__ ptok, int* __restrict__ posmap)
{
  __shared__ int cnt[NE], cur[NE];
  int tid = threadIdx.x;
  if (tid < NE) cnt[tid] = 0;
  __syncthreads();
  for (int t = tid; t < NT; t += 256){
    atomicAdd(&cnt[top_idx[2 * t]], 1);
    atomicAdd(&cnt[top_idx[2 * t + 1]], 1);
  }
  __syncthreads();
  if (tid == 0){
    int o = 0;
    for (int e = 0; e < NE; e++){ offsets[e] = o; cur[e] = o; counts[e] = cnt[e]; o += cnt[e]; }
  }
  __syncthreads();
  for (int t = tid; t < NT; t += 256){
#pragma unroll
    for (int sidx = 0; sidx < 2; sidx++){
      int e = top_idx[2 * t + sidx];
      int pos = atomicAdd(&cur[e], 1);
      ptok[pos] = t;
      posmap[2 * t + sidx] = pos;
    }
  }
}

// ---------------- MoE combine + residual + LN ----------------
__global__ __launch_bounds__(256) void moe_combine_ln_k(
    const float* __restrict__ OBuf, const int* __restrict__ posmap, const float* __restrict__ topw,
    const float* __restrict__ latin, const float* __restrict__ w, const float* __restrict__ b,
    float* __restrict__ lat)
{
  int t = blockIdx.x;
  int p0 = posmap[2 * t], p1 = posmap[2 * t + 1];
  float w0 = topw[2 * t], w1 = topw[2 * t + 1];
  __shared__ float sh[4];
  float x[3];
#pragma unroll
  for (int i = 0; i < 3; i++){
    int d = threadIdx.x + (i << 8);
    x[i] = w0 * OBuf[(long)p0 * Dm + d] + w1 * OBuf[(long)p1 * Dm + d] + latin[(long)t * Dm + d];
  }
  float s = blk_sum(x[0] + x[1] + x[2], sh);
  float mean = s * (1.0f / 768.0f);
  float vs = 0.f;
#pragma unroll
  for (int i = 0; i < 3; i++){ float tt = x[i] - mean; vs += tt * tt; }
  vs = blk_sum(vs, sh);
  float rstd = rsqrtf(vs * (1.0f / 768.0f) + 1e-5f);
#pragma unroll
  for (int i = 0; i < 3; i++){
    int d = threadIdx.x + (i << 8);
    lat[(long)t * Dm + d] = (x[i] - mean) * rstd * w[d] + b[d];
  }
}

} // namespace

extern "C" void kernel_launch(void* const* d_in, const int* in_sizes, int n_in,
                              void* d_out, int out_size, void* d_ws, size_t ws_size,
                              hipStream_t stream)
{
  (void)in_sizes; (void)n_in; (void)out_size; (void)ws_size;
  const float* images    = (const float*)d_in[0];
  const int*   type_ids  = (const int*)d_in[1];
  const float* noise     = (const float*)d_in[2];
  const float* conv_w    = (const float*)d_in[3];
  const float* conv_b    = (const float*)d_in[4];
  const float* latents   = (const float*)d_in[5];
  const float* type_emb  = (const float*)d_in[6];
  const float* ca_in_w   = (const float*)d_in[7];
  const float* ca_in_b   = (const float*)d_in[8];
  const float* ca_out_w  = (const float*)d_in[9];
  const float* ca_out_b  = (const float*)d_in[10];
  const float* ca_ln_w   = (const float*)d_in[11];
  const float* ca_ln_b   = (const float*)d_in[12];
  const float* blk_in_w  = (const float*)d_in[13];
  const float* blk_in_b  = (const float*)d_in[14];
  const float* blk_out_w = (const float*)d_in[15];
  const float* blk_out_b = (const float*)d_in[16];
  const float* blk_ln1_w = (const float*)d_in[17];
  const float* blk_ln1_b = (const float*)d_in[18];
  const float* blk_ln2_w = (const float*)d_in[19];
  const float* blk_ln2_b = (const float*)d_in[20];
  const float* router_w  = (const float*)d_in[21];
  const float* router_b  = (const float*)d_in[22];
  const float* e_w1      = (const float*)d_in[23];
  const float* e_b1      = (const float*)d_in[24];
  const float* e_w2      = (const float*)d_in[25];
  const float* e_b2      = (const float*)d_in[26];

  float* ws      = (float*)d_ws;
  float* lat     = ws + OFF_LAT;
  float* qkv     = ws + OFF_QKV;
  float* obufM   = ws + OFF_QKV;   // alias (disjoint in time)
  float* S       = ws + OFF_S;
  float* Hbuf    = ws + OFF_S;     // alias (disjoint in time)
  float* ao      = ws + OFF_AO;
  float* tmp     = ws + OFF_TMP;
  float* viscol  = ws + OFF_COL;
  float* visible = ws + OFF_VIS;
  float* qq      = ws + OFF_QQ;
  float* kkvv    = ws + OFF_KKVV;
  float* topw    = ws + OFF_TOPW;
  int*   ibase   = (int*)(ws + OFF_INT);
  int*   ids     = ibase;
  int*   top_idx = ibase + 784;
  int*   posmap  = top_idx + 2048;
  int*   ptok    = posmap + 2048;
  int*   counts  = ptok + 2048;
  int*   offsets = counts + 8;

  float* out      = (float*)d_out;
  float* out_lat  = out;
  float* out_keep = out + (long)NT * Dm;
  float* out_mask = out_keep + BB * NV;

  dim3 blk(256);
  const float inv_sqrt_dh = 1.0f / sqrtf((float)DH_);

  // ---- prologue: mask ids, visible-only patch embed ----
  argsort_k<<<BB, blk, 0, stream>>>(noise, ids, out_keep, out_mask);
  im2col_k<<<BB * NV, blk, 0, stream>>>(images, ids, viscol);
  // conv as GEMM: visible = viscol @ conv_w^T + conv_b
  mgemm_k<true,false,false><<<dim3(6, 2, 1), blk, 0, stream>>>(
      viscol, Dm, 0, 0, conv_w, Dm, 0, 0, visible, Dm, 0, 0,
      BB * NV, Dm, Dm, Dm, 1, conv_b, 0, 1.0f, 0, nullptr, nullptr, nullptr, 1);
  pos_type_k<<<BB * NV, blk, 0, stream>>>(visible, ids, type_ids, type_emb);

  // ---- cross attention ----
  mgemm_k<true,false,false><<<dim3(6, 2, 1), blk, 0, stream>>>(
      latents, Dm, 0, 0, ca_in_w, Dm, 0, 0, qq, Dm, 0, 0,
      ML, Dm, Dm, Dm, 1, ca_in_b, 0, 1.0f, 0, nullptr, nullptr, nullptr, 1);
  mgemm_k<true,false,false><<<dim3(12, 2, 1), blk, 0, stream>>>(
      visible, Dm, 0, 0, ca_in_w + 768 * 768, Dm, 0, 0, kkvv, 1536, 0, 0,
      BB * NV, 1536, Dm, Dm, 1, ca_in_b + 768, 0, 1.0f, 0, nullptr, nullptr, nullptr, 1);
  mgemm_k<true,false,false><<<dim3(1, 2, BB * NH_), blk, 0, stream>>>(
      qq, Dm, 0, DH_,
      kkvv, 1536, (long)NV * 1536, DH_,
      S, 64, (long)NH_ * ML * 64, ML * 64,
      ML, NV, DH_, DH_, NH_, nullptr, 0, inv_sqrt_dh, 0, nullptr, nullptr, nullptr, 1);
  softmax_k<<<BB * NH_ * ML, blk, 0, stream>>>(S, NV, 64);
  mgemm_k<false,false,false><<<dim3(1, 2, BB * NH_), blk, 0, stream>>>(
      S, 64, (long)NH_ * ML * 64, ML * 64,
      kkvv + 768, 1536, (long)NV * 1536, DH_,
      ao, Dm, (long)ML * Dm, DH_,
      ML, DH_, 64, NV, NH_, nullptr, 0, 1.0f, 0, nullptr, nullptr, nullptr, 1);
  mgemm_k<true,false,false><<<dim3(6, 8, 1), blk, 0, stream>>>(
      ao, Dm, 0, 0, ca_out_w, Dm, 0, 0, tmp, Dm, 0, 0,
      NT, Dm, Dm, Dm, 1, ca_out_b, 0, 1.0f, 0, nullptr, nullptr, nullptr, 1);
  add_ln_k<<<NT, blk, 0, stream>>>(tmp, latents, ML, ca_ln_w, ca_ln_b, lat);

  // ---- transformer blocks ----
  for (int l = 0; l < NL; l++){
    mgemm_k<true,false,false><<<dim3(18, 8, 1), blk, 0, stream>>>(
        lat, Dm, 0, 0, blk_in_w + (long)l * 2304 * 768, Dm, 0, 0,
        qkv, 2304, 0, 0, NT, 2304, Dm, Dm, 1, blk_in_b + (long)l * 2304, 0, 1.0f, 0,
        nullptr, nullptr, nullptr, 1);
    mgemm_k<true,false,false><<<dim3(2, 2, BB * NH_), blk, 0, stream>>>(
        qkv, 2304, (long)ML * 2304, DH_,
        qkv + 768, 2304, (long)ML * 2304, DH_,
        S, ML, (long)NH_ * ML * ML, ML * ML,
        ML, ML, DH_, DH_, NH_, nullptr, 0, inv_sqrt_dh, 0, nullptr, nullptr, nullptr, 1);
    softmax_k<<<BB * NH_ * ML, blk, 0, stream>>>(S, ML, ML);
    mgemm_k<false,false,false><<<dim3(1, 2, BB * NH_), blk, 0, stream>>>(
        S, ML, (long)NH_ * ML * ML, ML * ML,
        qkv + 1536, 2304, (long)ML * 2304, DH_,
        ao, Dm, (long)ML * Dm, DH_,
        ML, DH_, ML, ML, NH_, nullptr, 0, 1.0f, 0, nullptr, nullptr, nullptr, 1);
    mgemm_k<true,false,false><<<dim3(6, 8, 1), blk, 0, stream>>>(
        ao, Dm, 0, 0, blk_out_w + (long)l * 768 * 768, Dm, 0, 0, tmp, Dm, 0, 0,
        NT, Dm, Dm, Dm, 1, blk_out_b + (long)l * 768, 0, 1.0f, 0, nullptr, nullptr, nullptr, 1);
    add_ln_k<<<NT, blk, 0, stream>>>(tmp, lat, 0,
        blk_ln1_w + (long)l * 768, blk_ln1_b + (long)l * 768, lat);

    // MoE
    router_k<<<NT, blk, 0, stream>>>(lat, router_w + (long)l * NE * Dm, router_b + (long)l * NE,
                                     top_idx, topw);
    scatter_k<<<1, blk, 0, stream>>>(top_idx, counts, offsets, ptok, posmap);
    mgemm_k<true,true,true><<<dim3(12, 128, 1), blk, 0, stream>>>(
        lat, Dm, 0, 0,
        e_w1 + (long)l * NE * FH_ * Dm, Dm, (long)FH_ * Dm, 0,
        Hbuf, FH_, 0, 0,
        0, FH_, Dm, Dm, 1, e_b1 + (long)l * NE * FH_, FH_, 1.0f, 1,
        counts, offsets, ptok, 16);
    mgemm_k<true,true,false><<<dim3(6, 128, 1), blk, 0, stream>>>(
        Hbuf, FH_, 0, 0,
        e_w2 + (long)l * NE * Dm * FH_, FH_, (long)Dm * FH_, 0,
        obufM, Dm, 0, 0,
        0, Dm, FH_, FH_, 1, e_b2 + (long)l * NE * Dm, Dm, 1.0f, 0,
        counts, offsets, ptok, 16);
    moe_combine_ln_k<<<NT, blk, 0, stream>>>(obufM, posmap, topw, lat,
        blk_ln2_w + (long)l * 768, blk_ln2_b + (long)l * 768,
        (l == NL - 1) ? out_lat : lat);
  }
}

// Round 3
// 1567.886 us; speedup vs baseline: 2.2596x; 1.3661x over previous
//
#include <hip/hip_runtime.h>
#include <math.h>

// ---------------------------------------------------------------------------
// DynamicPerceiverEncoder forward — bf16 MFMA everywhere, double-buffered
// global_load_lds GEMMs, fused flash attention.
// ---------------------------------------------------------------------------

namespace {

typedef unsigned short u16;
constexpr int Dm  = 768;
constexpr int NH_ = 8;
constexpr int ML  = 256;
constexpr int BB  = 4;
constexpr int NP  = 196;
constexpr int NV  = 49;
constexpr int NE  = 8;
constexpr int FH_ = 1536;
constexpr int NL  = 6;
constexpr int NT  = 1024;

typedef __attribute__((ext_vector_type(8))) short bf16x8;
typedef __attribute__((ext_vector_type(4))) float f32x4;

__device__ __forceinline__ u16 f2bf(float f){
  union { float f; unsigned u; } v; v.f = f;
  unsigned r = v.u + 0x7fffu + ((v.u >> 16) & 1u);
  return (u16)(r >> 16);
}
__device__ __forceinline__ void pack8(const float4& a, const float4& b, bf16x8& w){
  w[0]=(short)f2bf(a.x); w[1]=(short)f2bf(a.y); w[2]=(short)f2bf(a.z); w[3]=(short)f2bf(a.w);
  w[4]=(short)f2bf(b.x); w[5]=(short)f2bf(b.y); w[6]=(short)f2bf(b.z); w[7]=(short)f2bf(b.w);
}
__device__ __forceinline__ void gload16(const void* g, void* l){
  __builtin_amdgcn_global_load_lds(
      (const __attribute__((address_space(1))) unsigned int*)g,
      (__attribute__((address_space(3))) unsigned int*)l, 16, 0, 0);
}

// ---------------- block reductions ----------------
__device__ __forceinline__ float blk_sum(float v, float* sh){
#pragma unroll
  for (int off = 32; off; off >>= 1) v += __shfl_xor(v, off);
  int wid = threadIdx.x >> 6;
  if ((threadIdx.x & 63) == 0) sh[wid] = v;
  __syncthreads();
  v = sh[0] + sh[1] + sh[2] + sh[3];
  __syncthreads();
  return v;
}

// ---------------- f32 -> bf16 convert ----------------
__global__ __launch_bounds__(256) void cvt_k(const float* __restrict__ src,
                                             u16* __restrict__ dst, long n){
  long i = ((long)blockIdx.x * 256 + threadIdx.x) * 4;
  long stride = (long)gridDim.x * 1024;
  for (; i < n; i += stride){
    float4 v = *(const float4*)(src + i);
    ushort4 o;
    o.x = f2bf(v.x); o.y = f2bf(v.y); o.z = f2bf(v.z); o.w = f2bf(v.w);
    *(ushort4*)(dst + i) = o;
  }
}

// ---------------- argsort 196 per batch (stable) ----------------
__global__ __launch_bounds__(256) void argsort_k(
    const float* __restrict__ noise, int* __restrict__ ids,
    float* __restrict__ out_keep, float* __restrict__ out_mask)
{
  int b = blockIdx.x, tid = threadIdx.x;
  __shared__ float v[NP];
  __shared__ int ord[NP];
  if (tid < NP) v[tid] = noise[b * NP + tid];
  __syncthreads();
  if (tid < NP){
    float x = v[tid];
    int rank = 0;
    for (int j = 0; j < NP; j++){
      float y = v[j];
      rank += (y < x) || (y == x && j < tid);
    }
    ord[rank] = tid;
  }
  __syncthreads();
  if (tid < NP){
    int id = ord[tid];
    ids[b * NP + tid] = id;
    if (tid < NV) out_keep[b * NV + tid] = (float)id;
    else          out_mask[b * (NP - NV) + (tid - NV)] = (float)id;
  }
}

// ---------------- im2col of visible patches (writes bf16) ----------------
__global__ __launch_bounds__(256) void im2col_k(
    const float* __restrict__ images, const int* __restrict__ ids,
    u16* __restrict__ col)
{
  int bv = blockIdx.x;
  int b = bv / NV, v = bv % NV;
  int pid = ids[b * NP + v];
  int ph = pid / 14, pw = pid % 14;
  int t = threadIdx.x;
  int kh = t >> 4, kw = t & 15;
#pragma unroll
  for (int c = 0; c < 3; c++)
    col[(long)bv * Dm + c * 256 + t] =
      f2bf(images[((b * 3 + c) * 224 + ph * 16 + kh) * 224 + pw * 16 + kw]);
}

// ---------------- pos + type emb: vis_f -> vis_bf ----------------
__global__ __launch_bounds__(256) void pos_type_k(
    const float* __restrict__ vis_f, const int* __restrict__ ids,
    const int* __restrict__ type_ids, const float* __restrict__ type_emb,
    u16* __restrict__ vis_bf)
{
  int bv = blockIdx.x;
  int b = bv / NV, v = bv % NV;
  int pid = ids[b * NP + v];
  int ph = pid / 14, pw = pid % 14;
  int ty = type_ids[b];
  int t = threadIdx.x;
#pragma unroll
  for (int jj = 0; jj < 3; jj++){
    int d = t + (jj << 8);
    int q = d % 192, sect = d / 192;
    float omega = powf(10000.0f, -(float)q / 192.0f);
    float arg = (sect < 2 ? (float)pw : (float)ph) * omega;
    float pos = ((sect & 1) == 0) ? sinf(arg) : cosf(arg);
    vis_bf[(long)bv * Dm + d] = f2bf(vis_f[(long)bv * Dm + d] + pos + type_emb[(long)ty * Dm + d]);
  }
}

// ---------------- double-buffered bf16 MFMA GEMM (128x128, BK=32) ----------------
// A bf16 [M][lda]. B: BT layout rows=N: bf16 (gload) or f32 (reg-staged cvt).
// Outputs: Cf (f32) and/or Cb (bf16), either may be null.
template<bool BF16B, bool MOE, bool GATHER>
__global__ __launch_bounds__(256) void g2_k(
    const u16* __restrict__ A, int lda,
    const void* __restrict__ Bv, int ldb, long bSB,
    const float* __restrict__ bias, long biasE,
    float* __restrict__ Cf, u16* __restrict__ Cb, int ldc,
    int M, int N, int K, int act,
    const int* __restrict__ counts, const int* __restrict__ offsets,
    const int* __restrict__ ptok, int mbPerE)
{
  __shared__ __align__(16) short lsa[2][4096];
  __shared__ __align__(16) short lsb[2][4096];
  int t = threadIdx.x, lane = t & 63, wid = t >> 6;
  int n0 = blockIdx.x << 7;
  int m0, cnt = 0, off = 0;
  const u16* B16 = (const u16*)Bv;
  const float* B32 = (const float*)Bv;
  const float* bb = bias;
  if (MOE){
    int e = blockIdx.y / mbPerE, mb = blockIdx.y - e * mbPerE;
    cnt = counts[e]; m0 = mb << 7;
    if (m0 >= cnt) return;
    off = offsets[e];
    if (BF16B) B16 += (long)e * bSB; else B32 += (long)e * bSB;
    bb += (long)e * biasE;
  } else {
    m0 = blockIdx.y << 7;
  }

  long aoff[2];
#pragma unroll
  for (int i = 0; i < 2; i++){
    int idx = i * 256 + t, c = idx >> 7, r = idx & 127;
    int gl = m0 + r;
    long row;
    if (MOE) row = (gl < cnt) ? (GATHER ? (long)ptok[off + gl] : (long)(off + gl))
                              : (GATHER ? (long)ptok[off] : (long)off);
    else     row = (gl < M) ? gl : 0;
    aoff[i] = row * (long)lda + c * 8;
  }
  long boff[2] = {0, 0};
  int bcol = 0, bkh = 0;
  const float* b32p = nullptr;
  if (BF16B){
#pragma unroll
    for (int i = 0; i < 2; i++){
      int idx = i * 256 + t, c = idx >> 7, r = idx & 127;
      int gc = n0 + r; if (gc >= N) gc = 0;
      boff[i] = (long)gc * ldb + c * 8;
    }
  } else {
    bcol = t >> 1; bkh = (t & 1) << 4;
    int gc = n0 + bcol; if (gc >= N) gc = N - 1;
    b32p = B32 + (long)gc * ldb + bkh;
  }

  float4 br[4];
  auto stage = [&](int buf, int k0){
#pragma unroll
    for (int i = 0; i < 2; i++)
      gload16(A + aoff[i] + k0, &lsa[buf][(i * 256 + wid * 64) * 8]);
    if (BF16B){
#pragma unroll
      for (int i = 0; i < 2; i++)
        gload16(B16 + boff[i] + k0, &lsb[buf][(i * 256 + wid * 64) * 8]);
    } else {
#pragma unroll
      for (int j = 0; j < 4; j++) br[j] = *(const float4*)(b32p + k0 + j * 4);
    }
  };
  auto bwrite = [&](int buf){
    if (!BF16B){
      bf16x8 w0, w1;
      pack8(br[0], br[1], w0); pack8(br[2], br[3], w1);
      int c0 = bkh >> 3;
      *(bf16x8*)&lsb[buf][((c0    ) * 128 + bcol) * 8] = w0;
      *(bf16x8*)&lsb[buf][((c0 + 1) * 128 + bcol) * 8] = w1;
    }
  };

  f32x4 acc[4][4];
#pragma unroll
  for (int m = 0; m < 4; m++)
#pragma unroll
    for (int n = 0; n < 4; n++) acc[m][n] = (f32x4){0.f,0.f,0.f,0.f};

  int T = K >> 5;
  stage(0, 0);
  bwrite(0);
  __syncthreads();

  int wr = wid >> 1, wc = wid & 1, fr = lane & 15, lk = lane >> 4;
  for (int tt = 0; tt < T; tt++){
    int cur = tt & 1, nxt = cur ^ 1;
    if (tt + 1 < T) stage(nxt, (tt + 1) << 5);
    bf16x8 av[4], bv[4];
#pragma unroll
    for (int m = 0; m < 4; m++)
      av[m] = *(const bf16x8*)&lsa[cur][(lk * 128 + wr * 64 + m * 16 + fr) * 8];
#pragma unroll
    for (int n = 0; n < 4; n++)
      bv[n] = *(const bf16x8*)&lsb[cur][(lk * 128 + wc * 64 + n * 16 + fr) * 8];
#pragma unroll
    for (int m = 0; m < 4; m++)
#pragma unroll
      for (int n = 0; n < 4; n++)
        acc[m][n] = __builtin_amdgcn_mfma_f32_16x16x32_bf16(av[m], bv[n], acc[m][n], 0, 0, 0);
    if (tt + 1 < T) bwrite(nxt);
    __syncthreads();
  }

#pragma unroll
  for (int m = 0; m < 4; m++)
#pragma unroll
  for (int i = 0; i < 4; i++){
    int rl = m0 + wr * 64 + m * 16 + lk * 4 + i;
    bool ok = MOE ? (rl < cnt) : (rl < M);
    if (!ok) continue;
    long grow = MOE ? (long)(off + rl) : (long)rl;
#pragma unroll
    for (int n = 0; n < 4; n++){
      int col = n0 + wc * 64 + n * 16 + fr;
      if (col >= N) continue;
      float v = acc[m][n][i] + bb[col];
      if (act) v = 0.5f * v * (1.0f + erff(v * 0.70710678118654752f));
      if (Cf) Cf[grow * (long)ldc + col] = v;
      if (Cb) Cb[grow * (long)ldc + col] = f2bf(v);
    }
  }
}

// ---------------- fused flash attention ----------------
// Per block: one (b,h), 128 q-rows. Full S in regs, softmax, PV via LDS P/VT.
template<int KVCAP>
__global__ __launch_bounds__(256) void flash_k(
    const u16* __restrict__ Qp, int ldq, int qBatchRows,
    const u16* __restrict__ Kp, int ldk,
    const u16* __restrict__ Vp, int ldv, int kvBatchRows,
    int qCol0, int kCol0, int vCol0,
    int kvLen, u16* __restrict__ Ob)
{
  constexpr int NF   = KVCAP / 16;
  constexpr int HALF = (KVCAP > 128) ? 128 : KVCAP;
  constexpr int NHF  = KVCAP / HALF;
  constexpr int NF2  = HALF / 16;

  __shared__ __align__(16) char sm[57344];
  short* smQ  = (short*)sm;                              // [12][128][8]
  short* smK0 = (short*)(sm + 24576);                    // [4][KVCAP][8]
  short* smK1 = (short*)(sm + 24576 + 4 * KVCAP * 16);
  short* smP  = (short*)sm;                              // [HALF/8][128][8]
  short* smVT = (short*)(sm + 32768);                    // [HALF/8][96][8]

  int t = threadIdx.x, lane = t & 63, wid = t >> 6;
  int fr = lane & 15, lk = lane >> 4;
  int qt = blockIdx.x, z = blockIdx.y, b = z >> 3, h = z & 7;
  int qRow0 = b * qBatchRows + qt * 128;
  int kvRow0 = b * kvBatchRows;
  int oRow0 = b * 256 + qt * 128;
  int qCol = qCol0 + h * 96, kCol = kCol0 + h * 96, vCol = vCol0 + h * 96;
  int wq0 = wid * 32;

  // stage Q (128 x 96)
#pragma unroll
  for (int i = 0; i < 6; i++){
    int idx = i * 256 + t, c = idx >> 7, r = idx & 127;
    *(bf16x8*)&smQ[idx * 8] = *(const bf16x8*)&Qp[(long)(qRow0 + r) * ldq + qCol + c * 8];
  }
  auto stageK = [&](int k0c, short* dst){
#pragma unroll
    for (int i = 0; i < (4 * KVCAP) / 256; i++){
      int idx = i * 256 + t, c = idx / KVCAP, col = idx % KVCAP;
      int kv = col < kvLen ? col : kvLen - 1;
      *(bf16x8*)&dst[idx * 8] =
        *(const bf16x8*)&Kp[(long)(kvRow0 + kv) * ldk + kCol + (k0c * 4 + c) * 8];
    }
  };
  stageK(0, smK0);
  __syncthreads();

  f32x4 acc[2][NF];
#pragma unroll
  for (int m = 0; m < 2; m++)
#pragma unroll
    for (int n = 0; n < NF; n++) acc[m][n] = (f32x4){0.f,0.f,0.f,0.f};

  for (int k0c = 0; k0c < 3; k0c++){
    short* curK = (k0c & 1) ? smK1 : smK0;
    if (k0c < 2) stageK(k0c + 1, (k0c & 1) ? smK0 : smK1);
    bf16x8 av[2];
#pragma unroll
    for (int m = 0; m < 2; m++)
      av[m] = *(const bf16x8*)&smQ[((k0c * 4 + lk) * 128 + wq0 + m * 16 + fr) * 8];
#pragma unroll
    for (int n = 0; n < NF; n++){
      bf16x8 bv = *(const bf16x8*)&curK[(lk * KVCAP + n * 16 + fr) * 8];
#pragma unroll
      for (int m = 0; m < 2; m++)
        acc[m][n] = __builtin_amdgcn_mfma_f32_16x16x32_bf16(av[m], bv, acc[m][n], 0, 0, 0);
    }
    __syncthreads();
  }

  // softmax (rows live in (lk,i); cols in (n,fr))
  const float scl = 0.10206207261596577f;   // 1/sqrt(96)
  float rinv[2][4];
#pragma unroll
  for (int m = 0; m < 2; m++)
#pragma unroll
  for (int i = 0; i < 4; i++){
    float mx = -3e38f;
#pragma unroll
    for (int n = 0; n < NF; n++){
      float v = acc[m][n][i] * scl;
      if (n * 16 + fr >= kvLen) v = -3e38f;
      acc[m][n][i] = v;
      mx = fmaxf(mx, v);
    }
#pragma unroll
    for (int s = 1; s < 16; s <<= 1) mx = fmaxf(mx, __shfl_xor(mx, s));
    float sum = 0.f;
#pragma unroll
    for (int n = 0; n < NF; n++){
      float p = __expf(acc[m][n][i] - mx);
      acc[m][n][i] = p;
      sum += p;
    }
#pragma unroll
    for (int s = 1; s < 16; s <<= 1) sum += __shfl_xor(sum, s);
    rinv[m][i] = 1.0f / sum;
  }

  // PV over halves
  f32x4 acco[2][6];
#pragma unroll
  for (int m = 0; m < 2; m++)
#pragma unroll
    for (int n = 0; n < 6; n++) acco[m][n] = (f32x4){0.f,0.f,0.f,0.f};

  for (int hf = 0; hf < NHF; hf++){
    if (hf) __syncthreads();
    // write P-half (own rows)
#pragma unroll
    for (int m = 0; m < 2; m++)
#pragma unroll
    for (int np = 0; np < NF2; np++){
      int n = hf * NF2 + np;
#pragma unroll
      for (int i = 0; i < 4; i++){
        int row = wq0 + m * 16 + lk * 4 + i;
        int cl = np * 16 + fr;
        smP[((cl >> 3) * 128 + row) * 8 + (cl & 7)] = (short)f2bf(acc[m][n][i]);
      }
    }
    // stage V^T half (cooperative)
    constexpr int G = (HALF * 96 / 8) / 256;
#pragma unroll
    for (int g = 0; g < G; g++){
      int flat = g * 256 + t;
      int kvl = flat / 12, dblk = (flat % 12) * 8;
      int kvg = hf * HALF + kvl;
      int kva = kvg < kvLen ? kvg : kvLen - 1;
      bf16x8 v = *(const bf16x8*)&Vp[(long)(kvRow0 + kva) * ldv + vCol + dblk];
      bool zz = kvg >= kvLen;
#pragma unroll
      for (int j = 0; j < 8; j++)
        smVT[((kvl >> 3) * 96 + dblk + j) * 8 + (kvl & 7)] = zz ? (short)0 : v[j];
    }
    __syncthreads();
#pragma unroll
    for (int kk = 0; kk < HALF / 32; kk++){
      bf16x8 pa[2];
#pragma unroll
      for (int m = 0; m < 2; m++)
        pa[m] = *(const bf16x8*)&smP[((kk * 4 + lk) * 128 + wq0 + m * 16 + fr) * 8];
#pragma unroll
      for (int n = 0; n < 6; n++){
        bf16x8 bv = *(const bf16x8*)&smVT[((kk * 4 + lk) * 96 + n * 16 + fr) * 8];
#pragma unroll
        for (int m = 0; m < 2; m++)
          acco[m][n] = __builtin_amdgcn_mfma_f32_16x16x32_bf16(pa[m], bv, acco[m][n], 0, 0, 0);
      }
    }
  }

#pragma unroll
  for (int m = 0; m < 2; m++)
#pragma unroll
  for (int n = 0; n < 6; n++)
#pragma unroll
  for (int i = 0; i < 4; i++){
    int row = oRow0 + wq0 + m * 16 + lk * 4 + i;
    int d = n * 16 + fr;
    Ob[(long)row * 768 + h * 96 + d] = f2bf(acco[m][n][i] * rinv[m][i]);
  }
}

// ---------------- add residual + LN (writes f32 + optional bf16) ----------------
__global__ __launch_bounds__(256) void add_ln_k(
    const float* __restrict__ X, const float* __restrict__ R, int rMod,
    const float* __restrict__ w, const float* __restrict__ b,
    float* __restrict__ outf, u16* __restrict__ outb)
{
  int row = blockIdx.x;
  int rrow = rMod ? (row % rMod) : row;
  __shared__ float sh[4];
  float x[3];
#pragma unroll
  for (int i = 0; i < 3; i++){
    int d = threadIdx.x + (i << 8);
    x[i] = X[(long)row * Dm + d] + R[(long)rrow * Dm + d];
  }
  float s = blk_sum(x[0] + x[1] + x[2], sh);
  float mean = s * (1.0f / 768.0f);
  float vs = 0.f;
#pragma unroll
  for (int i = 0; i < 3; i++){ float tt = x[i] - mean; vs += tt * tt; }
  vs = blk_sum(vs, sh);
  float rstd = rsqrtf(vs * (1.0f / 768.0f) + 1e-5f);
#pragma unroll
  for (int i = 0; i < 3; i++){
    int d = threadIdx.x + (i << 8);
    float o = (x[i] - mean) * rstd * w[d] + b[d];
    outf[(long)row * Dm + d] = o;
    if (outb) outb[(long)row * Dm + d] = f2bf(o);
  }
}

// ---------------- MoE router ----------------
__global__ __launch_bounds__(256) void router_k(
    const float* __restrict__ lat, const float* __restrict__ rw, const float* __restrict__ rb,
    int* __restrict__ top_idx, float* __restrict__ top_w)
{
  int t = blockIdx.x, tid = threadIdx.x;
  int e = tid >> 5, lane = tid & 31;
  const float* x = lat + (long)t * Dm;
  const float* w = rw + (long)e * Dm;
  float s = 0.f;
  for (int j = 0; j < 24; j++){ int d = lane + 32 * j; s += x[d] * w[d]; }
#pragma unroll
  for (int off = 16; off; off >>= 1) s += __shfl_xor(s, off);
  __shared__ float lg[NE];
  if (lane == 0) lg[e] = s + rb[e];
  __syncthreads();
  if (tid == 0){
    float m = -1e30f;
    for (int i = 0; i < NE; i++) m = fmaxf(m, lg[i]);
    float p[NE]; float se = 0.f;
    for (int i = 0; i < NE; i++){ p[i] = __expf(lg[i] - m); se += p[i]; }
    float inv = 1.0f / se;
    int i0 = 0, i1 = -1; float v0 = -1.f, v1 = -1.f;
    for (int i = 0; i < NE; i++){
      float pi = p[i] * inv;
      if (pi > v0){ v1 = v0; i1 = i0; v0 = pi; i0 = i; }
      else if (pi > v1){ v1 = pi; i1 = i; }
    }
    float w0 = 1.0f / (1.0f + __expf(v1 - v0));
    top_idx[2 * t] = i0; top_idx[2 * t + 1] = i1;
    top_w[2 * t] = w0;   top_w[2 * t + 1] = 1.0f - w0;
  }
}

// ---------------- group token-expert pairs ----------------
__global__ __launch_bounds__(256) void scatter_k(
    const int* __restrict__ top_idx, int* __restrict__ counts, int* __restrict__ offsets,
    int* __restrict__ ptok, int* __restrict__ posmap)
{
  __shared__ int cnt[NE], cur[NE];
  int tid = threadIdx.x;
  if (tid < NE) cnt[tid] = 0;
  __syncthreads();
  for (int t = tid; t < NT; t += 256){
    atomicAdd(&cnt[top_idx[2 * t]], 1);
    atomicAdd(&cnt[top_idx[2 * t + 1]], 1);
  }
  __syncthreads();
  if (tid == 0){
    int o = 0;
    for (int e = 0; e < NE; e++){ offsets[e] = o; cur[e] = o; counts[e] = cnt[e]; o += cnt[e]; }
  }
  __syncthreads();
  for (int t = tid; t < NT; t += 256){
#pragma unroll
    for (int sidx = 0; sidx < 2; sidx++){
      int e = top_idx[2 * t + sidx];
      int pos = atomicAdd(&cur[e], 1);
      ptok[pos] = t;
      posmap[2 * t + sidx] = pos;
    }
  }
}

// ---------------- MoE combine + residual + LN ----------------
__global__ __launch_bounds__(256) void moe_combine_ln_k(
    const float* __restrict__ OBuf, const int* __restrict__ posmap, const float* __restrict__ topw,
    const float* __restrict__ latin, const float* __restrict__ w, const float* __restrict__ b,
    float* __restrict__ outf, u16* __restrict__ outb)
{
  int t = blockIdx.x;
  int p0 = posmap[2 * t], p1 = posmap[2 * t + 1];
  float w0 = topw[2 * t], w1 = topw[2 * t + 1];
  __shared__ float sh[4];
  float x[3];
#pragma unroll
  for (int i = 0; i < 3; i++){
    int d = threadIdx.x + (i << 8);
    x[i] = w0 * OBuf[(long)p0 * Dm + d] + w1 * OBuf[(long)p1 * Dm + d] + latin[(long)t * Dm + d];
  }
  float s = blk_sum(x[0] + x[1] + x[2], sh);
  float mean = s * (1.0f / 768.0f);
  float vs = 0.f;
#pragma unroll
  for (int i = 0; i < 3; i++){ float tt = x[i] - mean; vs += tt * tt; }
  vs = blk_sum(vs, sh);
  float rstd = rsqrtf(vs * (1.0f / 768.0f) + 1e-5f);
#pragma unroll
  for (int i = 0; i < 3; i++){
    int d = threadIdx.x + (i << 8);
    float o = (x[i] - mean) * rstd * w[d] + b[d];
    outf[(long)t * Dm + d] = o;
    if (outb) outb[(long)t * Dm + d] = f2bf(o);
  }
}

} // namespace

extern "C" void kernel_launch(void* const* d_in, const int* in_sizes, int n_in,
                              void* d_out, int out_size, void* d_ws, size_t ws_size,
                              hipStream_t stream)
{
  (void)in_sizes; (void)n_in; (void)out_size; (void)ws_size;
  const float* images    = (const float*)d_in[0];
  const int*   type_ids  = (const int*)d_in[1];
  const float* noise     = (const float*)d_in[2];
  const float* conv_w    = (const float*)d_in[3];
  const float* conv_b    = (const float*)d_in[4];
  const float* latents   = (const float*)d_in[5];
  const float* type_emb  = (const float*)d_in[6];
  const float* ca_in_w   = (const float*)d_in[7];
  const float* ca_in_b   = (const float*)d_in[8];
  const float* ca_out_w  = (const float*)d_in[9];
  const float* ca_out_b  = (const float*)d_in[10];
  const float* ca_ln_w   = (const float*)d_in[11];
  const float* ca_ln_b   = (const float*)d_in[12];
  const float* blk_in_w  = (const float*)d_in[13];
  const float* blk_in_b  = (const float*)d_in[14];
  const float* blk_out_w = (const float*)d_in[15];
  const float* blk_out_b = (const float*)d_in[16];
  const float* blk_ln1_w = (const float*)d_in[17];
  const float* blk_ln1_b = (const float*)d_in[18];
  const float* blk_ln2_w = (const float*)d_in[19];
  const float* blk_ln2_b = (const float*)d_in[20];
  const float* router_w  = (const float*)d_in[21];
  const float* router_b  = (const float*)d_in[22];
  const float* e_w1      = (const float*)d_in[23];
  const float* e_b1      = (const float*)d_in[24];
  const float* e_w2      = (const float*)d_in[25];
  const float* e_b2      = (const float*)d_in[26];

  char* W = (char*)d_ws;
  float* lat   = (float*)(W + 0);              // 3,145,728
  float* tmp   = (float*)(W + 3145728);        // 3,145,728
  float* obuf  = (float*)(W + 6291456);        // 6,291,456
  float* vis_f = (float*)(W + 12582912);       //   602,112
  float* topw  = (float*)(W + 13185024);       //     8,192
  int*   ids      = (int*)(W + 13193216);
  int*   top_idx  = (int*)(W + 13197312);
  int*   posmap   = (int*)(W + 13205504);
  int*   ptok     = (int*)(W + 13213696);
  int*   counts   = (int*)(W + 13221888);
  int*   offsets  = (int*)(W + 13221952);
  u16* lat_bf    = (u16*)(W + 13258752);       // 1,572,864
  u16* ao_bf     = (u16*)(W + 14831616);       // 1,572,864
  u16* qkv_bf    = (u16*)(W + 16404480);       // 4,718,592
  u16* h_bf      = (u16*)(W + 21123072);       // 6,291,456
  u16* viscol_bf = (u16*)(W + 27414528);       //   301,056
  u16* vis_bf    = (u16*)(W + 27715584);       //   301,056
  u16* qq_bf     = (u16*)(W + 28016640);       //   393,216
  u16* kkvv_bf   = (u16*)(W + 28409856);       //   602,112
  u16* lat0_bf   = (u16*)(W + 29011968);       //   393,216
  u16* convw_bf  = (u16*)(W + 29405184);       // 1,179,648
  u16* caw_bf    = (u16*)(W + 30584832);       // 3,538,944
  u16* caow_bf   = (u16*)(W + 34123776);       // 1,179,648
  u16* blkin_bf  = (u16*)(W + 35303424);       // 21,233,664
  u16* blkout_bf = (u16*)(W + 56537088);       // 7,077,888

  float* out      = (float*)d_out;
  float* out_lat  = out;
  float* out_keep = out + (long)NT * Dm;
  float* out_mask = out_keep + BB * NV;

  dim3 blk(256);
  auto cg = [](long n){ long g = (n / 4 + 255) / 256; return (unsigned)(g > 4096 ? 4096 : g); };

  // ---- weight conversion (bf16) ----
  cvt_k<<<cg(589824),  blk, 0, stream>>>(conv_w,   convw_bf,  589824);
  cvt_k<<<cg(1769472), blk, 0, stream>>>(ca_in_w,  caw_bf,    1769472);
  cvt_k<<<cg(589824),  blk, 0, stream>>>(ca_out_w, caow_bf,   589824);
  cvt_k<<<cg(10616832),blk, 0, stream>>>(blk_in_w, blkin_bf,  10616832);
  cvt_k<<<cg(3538944), blk, 0, stream>>>(blk_out_w,blkout_bf, 3538944);
  cvt_k<<<cg(196608),  blk, 0, stream>>>(latents,  lat0_bf,   196608);

  // ---- prologue ----
  argsort_k<<<BB, blk, 0, stream>>>(noise, ids, out_keep, out_mask);
  im2col_k<<<BB * NV, blk, 0, stream>>>(images, ids, viscol_bf);
  g2_k<true,false,false><<<dim3(6, 2), blk, 0, stream>>>(
      viscol_bf, Dm, convw_bf, Dm, 0, conv_b, 0,
      vis_f, nullptr, Dm, BB * NV, Dm, Dm, 0, nullptr, nullptr, nullptr, 1);
  pos_type_k<<<BB * NV, blk, 0, stream>>>(vis_f, ids, type_ids, type_emb, vis_bf);

  // ---- cross attention ----
  g2_k<true,false,false><<<dim3(6, 2), blk, 0, stream>>>(
      lat0_bf, Dm, caw_bf, Dm, 0, ca_in_b, 0,
      nullptr, qq_bf, Dm, ML, Dm, Dm, 0, nullptr, nullptr, nullptr, 1);
  g2_k<true,false,false><<<dim3(12, 2), blk, 0, stream>>>(
      vis_bf, Dm, caw_bf + 768 * 768, Dm, 0, ca_in_b + 768, 0,
      nullptr, kkvv_bf, 1536, BB * NV, 1536, Dm, 0, nullptr, nullptr, nullptr, 1);
  flash_k<64><<<dim3(2, 32), blk, 0, stream>>>(
      qq_bf, Dm, 0, kkvv_bf, 1536, kkvv_bf, 1536, NV, 0, 0, 768, NV, ao_bf);
  g2_k<true,false,false><<<dim3(6, 8), blk, 0, stream>>>(
      ao_bf, Dm, caow_bf, Dm, 0, ca_out_b, 0,
      tmp, nullptr, Dm, NT, Dm, Dm, 0, nullptr, nullptr, nullptr, 1);
  add_ln_k<<<NT, blk, 0, stream>>>(tmp, latents, ML, ca_ln_w, ca_ln_b, lat, lat_bf);

  // ---- transformer blocks ----
  for (int l = 0; l < NL; l++){
    g2_k<true,false,false><<<dim3(18, 8), blk, 0, stream>>>(
        lat_bf, Dm, blkin_bf + (long)l * 2304 * 768, Dm, 0, blk_in_b + (long)l * 2304, 0,
        nullptr, qkv_bf, 2304, NT, 2304, Dm, 0, nullptr, nullptr, nullptr, 1);
    flash_k<256><<<dim3(2, 32), blk, 0, stream>>>(
        qkv_bf, 2304, ML, qkv_bf, 2304, qkv_bf, 2304, ML, 0, 768, 1536, ML, ao_bf);
    g2_k<true,false,false><<<dim3(6, 8), blk, 0, stream>>>(
        ao_bf, Dm, blkout_bf + (long)l * 768 * 768, Dm, 0, blk_out_b + (long)l * 768, 0,
        tmp, nullptr, Dm, NT, Dm, Dm, 0, nullptr, nullptr, nullptr, 1);
    add_ln_k<<<NT, blk, 0, stream>>>(tmp, lat, 0,
        blk_ln1_w + (long)l * 768, blk_ln1_b + (long)l * 768, lat, lat_bf);

    router_k<<<NT, blk, 0, stream>>>(lat, router_w + (long)l * NE * Dm,
                                     router_b + (long)l * NE, top_idx, topw);
    scatter_k<<<1, blk, 0, stream>>>(top_idx, counts, offsets, ptok, posmap);
    g2_k<false,true,true><<<dim3(12, 64), blk, 0, stream>>>(
        lat_bf, Dm, e_w1 + (long)l * NE * FH_ * Dm, Dm, (long)FH_ * Dm,
        e_b1 + (long)l * NE * FH_, FH_,
        nullptr, h_bf, FH_, 0, FH_, Dm, 1, counts, offsets, ptok, 8);
    g2_k<false,true,false><<<dim3(6, 64), blk, 0, stream>>>(
        h_bf, FH_, e_w2 + (long)l * NE * Dm * FH_, FH_, (long)Dm * FH_,
        e_b2 + (long)l * NE * Dm, Dm,
        obuf, nullptr, Dm, 0, Dm, FH_, 0, counts, offsets, ptok, 8);
    moe_combine_ln_k<<<NT, blk, 0, stream>>>(obuf, posmap, topw, lat,
        blk_ln2_w + (long)l * 768, blk_ln2_b + (long)l * 768,
        (l == NL - 1) ? out_lat : lat, (l == NL - 1) ? nullptr : lat_bf);
  }
}